// Round 7
// baseline (480.234 us; speedup 1.0000x reference)
//
#include <hip/hip_runtime.h>
#include <math.h>

#define H 512
#define S 65
#define SP 80               // padded s-dimension (rows 65..79 zero/garbage)
#define HS (H * S)          // 33280
#define PHS (H * SP)        // 40960
#define KS3 24
#define KS4 16
#define GRID 288            // widest phase (layer-1 kqv); 2 blocks/CU co-resident
#define NSLOT 12            // 1 registration + 11 data barriers

// Workspace layout (all buffers WRITE-ONCE per run -> no stale-line hazard):
//  y: PHS        kqvp: 18*PHS (layer1)   att1: 3*PHS   att2: PHS
//  plin1: 6*PHS  plin2: 6*PHS           kqvp2: 6*PHS  kqvp3: 6*PHS
//  y2: PHS       tpart: 24*1024         upart: 16*512
//  bar: census 8*32 u32 + NSLOT slots of 9*32 u32 (zeroed by captured memset)
//
// Coherence scheme (round 6):
//  - intermediates: PLAIN cached float4 stores (coalesced, write-combined in
//    L2) and PLAIN cached loads. Valid because every buffer is write-once.
//  - visibility: at each barrier, the LAST-arriving block on each physical
//    XCD (census via s_getreg XCC_ID) executes ONE __threadfence() ->
//    buffer_wbl2(+inv) for that L2 only, THEN bumps the master counter.
//    8 fences/barrier total instead of 288 per-word atomics.
//  - barrier counters: relaxed agent atomics (sc1, bypass L2) - validated.

// ---------------------------------------------------------------------------
// store helpers: now plain cached stores (write-combine in L2)
// ---------------------------------------------------------------------------
__device__ __forceinline__ void st1cv(float* p, float v) { *p = v; }
__device__ __forceinline__ void st4cv(float* p, float4 v) { *(float4*)p = v; }

// ---------------------------------------------------------------------------
// Registration barrier (no flush; nothing written yet). bid&7 classes.
// ---------------------------------------------------------------------------
__device__ __forceinline__ void gbar0(unsigned* slot, int bid) {
    __syncthreads();
    if (threadIdx.x == 0) {
        unsigned* sub    = slot + (bid & 7) * 32;
        unsigned* master = slot + 8 * 32;
        unsigned old = __hip_atomic_fetch_add(sub, 1u, __ATOMIC_RELAXED,
                                              __HIP_MEMORY_SCOPE_AGENT);
        if (old == (GRID / 8 - 1))
            __hip_atomic_fetch_add(master, 1u, __ATOMIC_RELAXED,
                                   __HIP_MEMORY_SCOPE_AGENT);
        while (__hip_atomic_load(master, __ATOMIC_RELAXED,
                                 __HIP_MEMORY_SCOPE_AGENT) < 8u)
            __builtin_amdgcn_s_sleep(2);
        asm volatile("" ::: "memory");
    }
    __syncthreads();
}

// ---------------------------------------------------------------------------
// Data barrier: last arriver per physical XCD flushes its L2 (one
// threadfence), then signals master. Pollers spin relaxed on master.
// ---------------------------------------------------------------------------
__device__ __forceinline__ void gbarx(unsigned* slot, unsigned xcd,
                                      unsigned census, unsigned nxcd) {
    __syncthreads();
    if (threadIdx.x == 0) {
        unsigned* sub    = slot + xcd * 32;
        unsigned* master = slot + 8 * 32;
        asm volatile("s_waitcnt vmcnt(0)" ::: "memory");   // stores in L2
        unsigned old = __hip_atomic_fetch_add(sub, 1u, __ATOMIC_RELAXED,
                                              __HIP_MEMORY_SCOPE_AGENT);
        if (old == census - 1u) {
            __threadfence();       // wbl2(+inv) for THIS XCD's L2 -> LLC
            __hip_atomic_fetch_add(master, 1u, __ATOMIC_RELAXED,
                                   __HIP_MEMORY_SCOPE_AGENT);
        }
        while (__hip_atomic_load(master, __ATOMIC_RELAXED,
                                 __HIP_MEMORY_SCOPE_AGENT) < nxcd)
            __builtin_amdgcn_s_sleep(16);
        asm volatile("" ::: "memory");
    }
    __syncthreads();
}

// ---------------------------------------------------------------------------
__device__ __forceinline__ void mac4(float4& c, float ax, float ay, float az,
                                     float aw, const float4& w0, const float4& w1,
                                     const float4& w2, const float4& w3) {
    c.x = fmaf(ax, w0.x, c.x); c.y = fmaf(ax, w0.y, c.y);
    c.z = fmaf(ax, w0.z, c.z); c.w = fmaf(ax, w0.w, c.w);
    c.x = fmaf(ay, w1.x, c.x); c.y = fmaf(ay, w1.y, c.y);
    c.z = fmaf(ay, w1.z, c.z); c.w = fmaf(ay, w1.w, c.w);
    c.x = fmaf(az, w2.x, c.x); c.y = fmaf(az, w2.y, c.y);
    c.z = fmaf(az, w2.z, c.z); c.w = fmaf(az, w2.w, c.w);
    c.x = fmaf(aw, w3.x, c.x); c.y = fmaf(aw, w3.y, c.y);
    c.z = fmaf(aw, w3.z, c.z); c.w = fmaf(aw, w3.w, c.w);
}

// ---------------------------------------------------------------------------
// KQV GEMM task (layers 2-3). Cached loads; plain stores.
// ---------------------------------------------------------------------------
__device__ __forceinline__ void kqv_task(const float* __restrict__ wq,
                                         const float* __restrict__ wk,
                                         const float* __restrict__ wv,
                                         int mat0,
                                         const float* __restrict__ yT,
                                         float* __restrict__ part,
                                         int task, int t,
                                         float* __restrict__ smem) {
    int slot  = task / 96;
    int r96   = task - slot * 96;
    int which = r96 >> 5;
    int xx    = r96 & 31;
    int mat   = mat0 + slot;
    const float* W = (which == 0 ? wk : (which == 1 ? wq : wv)) + (size_t)mat * H * H;

    int n0   = (xx & 15) * 32;
    int kidx = xx >> 4;

    float* Wt = smem;           // [64*32], swizzled
    float* As = smem + 2048;    // [SP*68], stride 68 conflict-free

    int nq = t & 7;
    int g  = t >> 3;
    bool r2 = (g < 16);

    float4 acc0 = {0,0,0,0}, acc1 = {0,0,0,0}, acc2 = {0,0,0,0};

    for (int ch = 0; ch < 4; ++ch) {
        int kc0 = kidx * 256 + ch * 64;
#pragma unroll
        for (int c = 0; c < 2; ++c) {
            int f = c * 256 + t;
            int wn  = f >> 4;
            int kf4 = f & 15;
            float4 w4 = *(const float4*)(W + (size_t)(n0 + wn) * H + kc0 + 4 * kf4);
            int sw = ((wn >> 2) ^ (kf4 & 7));
            int base = (4 * kf4) * 32 + 4 * sw + (wn & 3);
            Wt[base     ] = w4.x;
            Wt[base + 32] = w4.y;
            Wt[base + 64] = w4.z;
            Wt[base + 96] = w4.w;
        }
#pragma unroll
        for (int c = 0; c < 5; ++c) {
            int f = c * 256 + t;
            int as  = f >> 4;
            int kf4 = f & 15;
            *(float4*)(&As[as * 68 + 4 * kf4]) =
                *(const float4*)(yT + (size_t)as * H + kc0 + 4 * kf4);
        }
        __syncthreads();

#pragma unroll
        for (int k4 = 0; k4 < 16; ++k4) {
            int swc = 4 * (nq ^ (k4 & 7));
            float4 w0 = *(const float4*)(&Wt[(4 * k4 + 0) * 32 + swc]);
            float4 w1 = *(const float4*)(&Wt[(4 * k4 + 1) * 32 + swc]);
            float4 w2 = *(const float4*)(&Wt[(4 * k4 + 2) * 32 + swc]);
            float4 w3 = *(const float4*)(&Wt[(4 * k4 + 3) * 32 + swc]);
            {
                float4 a = *(const float4*)(&As[g * 68 + 4 * k4]);
                mac4(acc0, a.x, a.y, a.z, a.w, w0, w1, w2, w3);
            }
            {
                float4 a = *(const float4*)(&As[(g + 32) * 68 + 4 * k4]);
                mac4(acc1, a.x, a.y, a.z, a.w, w0, w1, w2, w3);
            }
            if (r2) {
                float4 a = *(const float4*)(&As[(g + 64) * 68 + 4 * k4]);
                mac4(acc2, a.x, a.y, a.z, a.w, w0, w1, w2, w3);
            }
        }
        __syncthreads();
    }

    float* P = part + (size_t)((slot * 3 + which) * 2 + kidx) * PHS;
    st4cv(P + (size_t)g * H + n0 + 4 * nq, acc0);
    st4cv(P + (size_t)(g + 32) * H + n0 + 4 * nq, acc1);
    if (r2) st4cv(P + (size_t)(g + 64) * H + n0 + 4 * nq, acc2);
}

// ---------------------------------------------------------------------------
// Layer-1 KQV with embed fused: As[s][k] = emb[k*S+s]*x[s] (bit-identical).
// ---------------------------------------------------------------------------
__device__ __forceinline__ void kqv1_task(const float* __restrict__ wq,
                                          const float* __restrict__ wk,
                                          const float* __restrict__ wv,
                                          const float* __restrict__ emb,
                                          float* __restrict__ part,
                                          int task, int t,
                                          float* __restrict__ smem,
                                          const float* __restrict__ xv) {
    int slot  = task / 96;
    int r96   = task - slot * 96;
    int which = r96 >> 5;
    int xx    = r96 & 31;
    const float* W = (which == 0 ? wk : (which == 1 ? wq : wv)) + (size_t)slot * H * H;

    int n0   = (xx & 15) * 32;
    int kidx = xx >> 4;

    float* Wt = smem;
    float* As = smem + 2048;

    int nq = t & 7;
    int g  = t >> 3;
    bool r2 = (g < 16);

    float4 acc0 = {0,0,0,0}, acc1 = {0,0,0,0}, acc2 = {0,0,0,0};

    for (int ch = 0; ch < 4; ++ch) {
        int kc0 = kidx * 256 + ch * 64;
#pragma unroll
        for (int c = 0; c < 2; ++c) {
            int f = c * 256 + t;
            int wn  = f >> 4;
            int kf4 = f & 15;
            float4 w4 = *(const float4*)(W + (size_t)(n0 + wn) * H + kc0 + 4 * kf4);
            int sw = ((wn >> 2) ^ (kf4 & 7));
            int base = (4 * kf4) * 32 + 4 * sw + (wn & 3);
            Wt[base     ] = w4.x;
            Wt[base + 32] = w4.y;
            Wt[base + 64] = w4.z;
            Wt[base + 96] = w4.w;
        }
#pragma unroll
        for (int c = 0; c < 5; ++c) {
            int f = c * 256 + t;
            int as  = (f & 15) + 16 * c;     // 0..79
            int kf4 = (f >> 4) & 15;         // 0..15
            int k0 = kc0 + 4 * kf4;
            float xs = xv[as];
            float4 v;
            v.x = emb[(size_t)(k0 + 0) * S + as] * xs;
            v.y = emb[(size_t)(k0 + 1) * S + as] * xs;
            v.z = emb[(size_t)(k0 + 2) * S + as] * xs;
            v.w = emb[(size_t)(k0 + 3) * S + as] * xs;
            *(float4*)(&As[as * 68 + 4 * kf4]) = v;
        }
        __syncthreads();

#pragma unroll
        for (int k4 = 0; k4 < 16; ++k4) {
            int swc = 4 * (nq ^ (k4 & 7));
            float4 w0 = *(const float4*)(&Wt[(4 * k4 + 0) * 32 + swc]);
            float4 w1 = *(const float4*)(&Wt[(4 * k4 + 1) * 32 + swc]);
            float4 w2 = *(const float4*)(&Wt[(4 * k4 + 2) * 32 + swc]);
            float4 w3 = *(const float4*)(&Wt[(4 * k4 + 3) * 32 + swc]);
            {
                float4 a = *(const float4*)(&As[g * 68 + 4 * k4]);
                mac4(acc0, a.x, a.y, a.z, a.w, w0, w1, w2, w3);
            }
            {
                float4 a = *(const float4*)(&As[(g + 32) * 68 + 4 * k4]);
                mac4(acc1, a.x, a.y, a.z, a.w, w0, w1, w2, w3);
            }
            if (r2) {
                float4 a = *(const float4*)(&As[(g + 64) * 68 + 4 * k4]);
                mac4(acc2, a.x, a.y, a.z, a.w, w0, w1, w2, w3);
            }
        }
        __syncthreads();
    }

    float* P = part + (size_t)((slot * 3 + which) * 2 + kidx) * PHS;
    st4cv(P + (size_t)g * H + n0 + 4 * nq, acc0);
    st4cv(P + (size_t)(g + 32) * H + n0 + 4 * nq, acc1);
    if (r2) st4cv(P + (size_t)(g + 64) * H + n0 + 4 * nq, acc2);
}

// ---------------------------------------------------------------------------
__device__ __forceinline__ float score_part(const float* __restrict__ Q0,
                                            const float* __restrict__ Q1,
                                            const float* __restrict__ ka,
                                            int b, int t) {
    const float4* q0 = (const float4*)(Q0 + (size_t)b * H) + t * 32;
    const float4* q1 = (const float4*)(Q1 + (size_t)b * H) + t * 32;
    const float4* kl = (const float4*)ka + t * 32;
    float4 c0 = {0,0,0,0}, c1 = {0,0,0,0};
#pragma unroll
    for (int u = 0; u < 32; u += 2) {
        float4 qa = q0[u], qb = q1[u], k0 = kl[u];
        float4 qc = q0[u+1], qd = q1[u+1], k1 = kl[u+1];
        c0.x = fmaf(k0.x, qa.x + qb.x, c0.x);
        c0.y = fmaf(k0.y, qa.y + qb.y, c0.y);
        c0.z = fmaf(k0.z, qa.z + qb.z, c0.z);
        c0.w = fmaf(k0.w, qa.w + qb.w, c0.w);
        c1.x = fmaf(k1.x, qc.x + qd.x, c1.x);
        c1.y = fmaf(k1.y, qc.y + qd.y, c1.y);
        c1.z = fmaf(k1.z, qc.z + qd.z, c1.z);
        c1.w = fmaf(k1.w, qc.w + qd.w, c1.w);
    }
    return ((c0.x + c0.y) + (c0.z + c0.w)) + ((c1.x + c1.y) + (c1.z + c1.w));
}

// ---------------------------------------------------------------------------
__device__ __forceinline__ void attn_task(const float* __restrict__ base,
                                          float* __restrict__ ao,
                                          int a, int tid,
                                          float* __restrict__ smem) {
    const float* K0 = base;
    const float* K1 = base + PHS;
    const float* Q0 = base + 2 * (size_t)PHS;
    const float* Q1 = base + 3 * (size_t)PHS;
    const float* V0 = base + 4 * (size_t)PHS;
    const float* V1 = base + 5 * (size_t)PHS;

    float* ka  = smem;          // 512
    float* sp  = smem + 512;    // 4*65
    float* smv = smem + 772;    // 65
    float* p   = smem + 837;    // 65

    ka[tid]       = K0[(size_t)a * H + tid]       + K1[(size_t)a * H + tid];
    ka[tid + 256] = K0[(size_t)a * H + tid + 256] + K1[(size_t)a * H + tid + 256];
    __syncthreads();

    {
        int b = tid & 63;
        int t = tid >> 6;
        sp[t * 65 + b] = score_part(Q0, Q1, ka, b, t);
        if (tid < 4) sp[tid * 65 + 64] = score_part(Q0, Q1, ka, 64, tid);
    }
    __syncthreads();

    if (tid < S) {
        smv[tid] = (sp[tid] + sp[65 + tid]) + (sp[130 + tid] + sp[195 + tid]);
    }
    __syncthreads();

    float maxv = -INFINITY;
    for (int i = 0; i < S; ++i) maxv = fmaxf(maxv, smv[i]);
    float sum = 0.0f;
    for (int i = 0; i < S; ++i) sum += expf(smv[i] - maxv);
    float inv = 1.0f / sum;
    if (tid < S) p[tid] = expf(smv[tid] - maxv) * inv;
    __syncthreads();

#pragma unroll
    for (int rep = 0; rep < 2; ++rep) {
        int hh = tid + rep * 256;
        float a0 = 0.f, a1 = 0.f;
#pragma unroll 4
        for (int b = 0; b < 64; b += 2) {
            a0 = fmaf(p[b    ], V0[(size_t)(b    ) * H + hh] + V1[(size_t)(b    ) * H + hh], a0);
            a1 = fmaf(p[b + 1], V0[(size_t)(b + 1) * H + hh] + V1[(size_t)(b + 1) * H + hh], a1);
        }
        a0 = fmaf(p[64], V0[(size_t)64 * H + hh] + V1[(size_t)64 * H + hh], a0);
        st1cv(ao + hh, a0 + a1);
    }
    __syncthreads();
}

// ---------------------------------------------------------------------------
__device__ __forceinline__ void lin4row_dev(float* __restrict__ smem,
                                            const float* __restrict__ att,
                                            int col0,
                                            const float* __restrict__ L,
                                            float* __restrict__ dst,
                                            int s0, int tid) {
    float* Ar   = smem;                          // 4*256
    float4* red = (float4*)(smem + 1024);        // 4*128 float4

    {
        int rr = tid >> 6;
        int cc = tid & 63;
        *(float4*)(&Ar[rr * 256 + cc * 4]) =
            *(const float4*)(att + (size_t)(s0 + rr) * H + col0 + cc * 4);
    }
    __syncthreads();

    int h4 = (tid & 127) * 4;
    int jh = tid >> 7;
    const float* Lj = L + (size_t)(jh * 128) * H + h4;
    const float* A0 = Ar + jh * 128;

    float4 c0 = {0,0,0,0}, c1 = {0,0,0,0}, c2 = {0,0,0,0}, c3 = {0,0,0,0};
#pragma unroll 8
    for (int j = 0; j < 128; ++j) {
        float4 L4 = *(const float4*)(Lj + (size_t)j * H);
        float a0 = A0[j], a1 = A0[256 + j], a2 = A0[512 + j], a3 = A0[768 + j];
        c0.x = fmaf(a0, L4.x, c0.x); c0.y = fmaf(a0, L4.y, c0.y);
        c0.z = fmaf(a0, L4.z, c0.z); c0.w = fmaf(a0, L4.w, c0.w);
        c1.x = fmaf(a1, L4.x, c1.x); c1.y = fmaf(a1, L4.y, c1.y);
        c1.z = fmaf(a1, L4.z, c1.z); c1.w = fmaf(a1, L4.w, c1.w);
        c2.x = fmaf(a2, L4.x, c2.x); c2.y = fmaf(a2, L4.y, c2.y);
        c2.z = fmaf(a2, L4.z, c2.z); c2.w = fmaf(a2, L4.w, c2.w);
        c3.x = fmaf(a3, L4.x, c3.x); c3.y = fmaf(a3, L4.y, c3.y);
        c3.z = fmaf(a3, L4.z, c3.z); c3.w = fmaf(a3, L4.w, c3.w);
    }

    if (jh == 1) {
        int x = tid & 127;
        red[x] = c0; red[128 + x] = c1; red[256 + x] = c2; red[384 + x] = c3;
    }
    __syncthreads();
    if (jh == 0) {
        float4 r0 = red[tid], r1 = red[128 + tid], r2 = red[256 + tid], r3 = red[384 + tid];
        c0.x += r0.x; c0.y += r0.y; c0.z += r0.z; c0.w += r0.w;
        c1.x += r1.x; c1.y += r1.y; c1.z += r1.z; c1.w += r1.w;
        c2.x += r2.x; c2.y += r2.y; c2.z += r2.z; c2.w += r2.w;
        c3.x += r3.x; c3.y += r3.y; c3.z += r3.z; c3.w += r3.w;
        st4cv(dst + (size_t)(s0 + 0) * H + h4, c0);
        st4cv(dst + (size_t)(s0 + 1) * H + h4, c1);
        st4cv(dst + (size_t)(s0 + 2) * H + h4, c2);
        st4cv(dst + (size_t)(s0 + 3) * H + h4, c3);
    }
    __syncthreads();
}

// ---------------------------------------------------------------------------
__device__ __forceinline__ void lin3_slice(const float* __restrict__ att1,
                                           const float* __restrict__ lin3,
                                           float* __restrict__ tpart,
                                           int idx, int tid) {
    int j2 = (idx & 3) * 256 + tid;
    int ks = idx >> 2;                    // 0..15
    const float* row = att1 + (size_t)(ks >> 3) * PHS + (size_t)64 * H;
    int j0 = (ks & 7) * 64;
    int jbase = ks * 64;
    float a0 = 0.f, a1 = 0.f, a2 = 0.f, a3 = 0.f;
    for (int j = 0; j < 64; j += 4) {
        a0 = fmaf(row[j0 + j + 0], lin3[(size_t)(jbase + j + 0) * 1024 + j2], a0);
        a1 = fmaf(row[j0 + j + 1], lin3[(size_t)(jbase + j + 1) * 1024 + j2], a1);
        a2 = fmaf(row[j0 + j + 2], lin3[(size_t)(jbase + j + 2) * 1024 + j2], a2);
        a3 = fmaf(row[j0 + j + 3], lin3[(size_t)(jbase + j + 3) * 1024 + j2], a3);
    }
    st1cv(tpart + ks * 1024 + j2, (a0 + a1) + (a2 + a3));
}

// ---------------------------------------------------------------------------
__global__ void __launch_bounds__(256, 2)
reversi_mega(const float* __restrict__ inputs, const float* __restrict__ emb,
             const float* __restrict__ wq, const float* __restrict__ wk,
             const float* __restrict__ wv, const float* __restrict__ lin1,
             const float* __restrict__ lin2, const float* __restrict__ lin3,
             const float* __restrict__ lin4, const float* __restrict__ lin5,
             float* __restrict__ out, float* __restrict__ ws) {
    __shared__ __align__(16) float smem[7568];   // 30272 B (union + xv[80])
    __shared__ unsigned sxcd, scen, snx;

    float* y     = ws;                  // layer-1 output (P4)
    float* kqvp  = y     + PHS;         // 18*PHS layer-1 kqv (P1)
    float* att1  = kqvp  + 18 * PHS;    // 3*PHS  (P2)
    float* att2  = att1  + 3 * PHS;     // PHS    (P6)
    float* plin1 = att2  + PHS;         // 6*PHS  (P3)
    float* plin2 = plin1 + 6 * PHS;     // 6*PHS  (P3 segs0-3, P7 segs4-5)
    float* kqvp2 = plin2 + 6 * PHS;     // 6*PHS  layer-2 kqv (P5)
    float* kqvp3 = kqvp2 + 6 * PHS;     // 6*PHS  layer-3 kqv (P9)
    float* y2    = kqvp3 + 6 * PHS;     // PHS    layer-2 output (P8)
    float* tpart = y2    + PHS;         // 24*1024
    float* upart = tpart + KS3 * 1024;  // 16*512
    unsigned* bar    = (unsigned*)(upart + KS4 * 512);
    unsigned* census = bar;             // 8 counters, 128 B apart
    unsigned* slots  = bar + 256;       // NSLOT slots of 9*32

    int tid  = threadIdx.x;
    int bid  = blockIdx.x;
    int nbk  = gridDim.x;
    int cls  = bid & 7;     // task-partition class (coverage-exact)
    int rank = bid >> 3;    // 0..35 within class

    // ---- registration: physical-XCD census, then full-grid barrier ----
    if (tid == 0) {
        unsigned x;
        asm volatile("s_getreg_b32 %0, hwreg(HW_REG_XCC_ID)" : "=s"(x));
        x &= 7u;
        sxcd = x;
        __hip_atomic_fetch_add(census + x * 32, 1u, __ATOMIC_RELAXED,
                               __HIP_MEMORY_SCOPE_AGENT);
    }
    __syncthreads();
    gbar0(slots, bid);
    if (tid == 0) {
        unsigned n = 0, c = 0;
        for (int i = 0; i < 8; ++i) {
            unsigned v = __hip_atomic_load(census + i * 32, __ATOMIC_RELAXED,
                                           __HIP_MEMORY_SCOPE_AGENT);
            if (v) ++n;
            if ((unsigned)i == sxcd) c = v;
        }
        scen = c; snx = n;
    }
    __syncthreads();
    unsigned xcd = sxcd, cen = scen, nx = snx;
    int bi = 1;

    // ---- P1: layer-1 KQV (mats 0..2), embed fused, 288 tasks ----
    float* xv = smem + 7488;
    if (tid < 80) {
        float xvv = 0.f;
        if (tid < S) xvv = (tid == 64) ? 1.0f : inputs[tid];
        xv[tid] = xvv;
    }
    __syncthreads();
    for (int task = bid; task < 288; task += nbk)
        kqv1_task(wq, wk, wv, emb, kqvp, task, tid, smem, xv);
    gbarx(slots + (size_t)bi * 9 * 32, xcd, cen, nx); ++bi;

    // ---- P2: layer-1 attention, slot-affine classes ----
    {
        int slot, r;
        if (cls < 3)      { slot = 0; r = cls * 36 + rank; }
        else if (cls < 5) { slot = 1; r = (cls - 3) * 36 + rank; }
        else              { slot = 2; r = (cls - 5) * 36 + rank; }
        if (r < 65)
            attn_task(kqvp + (size_t)slot * 6 * PHS,
                      att1 + (size_t)slot * PHS + (size_t)r * H, r, tid, smem);
    }
    gbarx(slots + (size_t)bi * 9 * 32, xcd, cen, nx); ++bi;

    // ---- P3: mega_lin, seg-affine classes ----
    {
        if (cls < 6) {
            if (rank < 17) {
                int seg = cls;
                lin4row_dev(smem, att1 + (size_t)(seg >> 1) * PHS,
                            (seg & 1) * 256, lin1 + (size_t)(seg * 256) * H,
                            plin1 + (size_t)seg * PHS, rank * 4, tid);
            } else {
                int spare = cls * 19 + (rank - 17);   // 0..113
                if (spare < 64) lin3_slice(att1, lin3, tpart, spare, tid);
            }
        } else {
            if (rank < 34) {
                int s2 = (cls - 6) * 2 + (rank / 17); // lin2 seg 0..3
                int pp = rank % 17;
                lin4row_dev(smem, att1 + (size_t)(s2 >> 1) * PHS,
                            (s2 & 1) * 256, lin2 + (size_t)(s2 * 256) * H,
                            plin2 + (size_t)s2 * PHS, pp * 4, tid);
            }
        }
    }
    gbarx(slots + (size_t)bi * 9 * 32, xcd, cen, nx); ++bi;

    // ---- P4: combine plin1 -> y (relu); pad rows zeroed ----
    for (int task = bid; task < PHS / 256; task += nbk) {
        int i = task * 256 + tid;
        if (i < HS) {
            float s = 0.f;
#pragma unroll
            for (int p = 0; p < 6; ++p) s += plin1[(size_t)p * PHS + i];
            st1cv(y + i, fmaxf(s, 0.0f));
        } else {
            st1cv(y + i, 0.f);
        }
    }
    gbarx(slots + (size_t)bi * 9 * 32, xcd, cen, nx); ++bi;

    // ---- P5: layer-2 KQV (mat 5) -> kqvp2, 96 tasks ----
    for (int task = bid; task < 96; task += nbk)
        kqv_task(wq, wk, wv, 5, y, kqvp2, task, tid, smem);
    gbarx(slots + (size_t)bi * 9 * 32, xcd, cen, nx); ++bi;

    // ---- P6: layer-2 attention, classes 0,1 ----
    if (cls < 2) {
        int r = cls * 36 + rank;
        if (r < 65)
            attn_task(kqvp2, att2 + (size_t)r * H, r, tid, smem);
    }
    gbarx(slots + (size_t)bi * 9 * 32, xcd, cen, nx); ++bi;

    // ---- P7: lin2 segs 4,5 from att2 ----
    if (cls < 2 && rank < 17) {
        int seg = 4 + cls;
        lin4row_dev(smem, att2, (seg & 1) * 256, lin2 + (size_t)(seg * 256) * H,
                    plin2 + (size_t)seg * PHS, rank * 4, tid);
    }
    gbarx(slots + (size_t)bi * 9 * 32, xcd, cen, nx); ++bi;

    // ---- P8: combine plin2 -> y2 (relu); pads zeroed ----
    for (int task = bid; task < PHS / 256; task += nbk) {
        int i = task * 256 + tid;
        if (i < HS) {
            float s = 0.f;
#pragma unroll
            for (int p = 0; p < 6; ++p) s += plin2[(size_t)p * PHS + i];
            st1cv(y2 + i, fmaxf(s, 0.0f));
        } else {
            st1cv(y2 + i, 0.f);
        }
    }
    gbarx(slots + (size_t)bi * 9 * 32, xcd, cen, nx); ++bi;

    // ---- P9: layer-3 KQV (mat 8) -> kqvp3, 96 tasks ----
    for (int task = bid; task < 96; task += nbk)
        kqv_task(wq, wk, wv, 8, y2, kqvp3, task, tid, smem);
    gbarx(slots + (size_t)bi * 9 * 32, xcd, cen, nx); ++bi;

    // ---- P10: layer-3 attention (row 64) + lin3 slices 16..23 ----
    if (cls < 4 && rank < 8) {
        int task = cls * 8 + rank;            // 0..31
        int xb = task & 3;
        int ks = 16 + (task >> 2);
        int j2 = xb * 256 + tid;
        int j0 = (ks & 7) * 64;

        const float* K0 = kqvp3;
        const float* K1 = kqvp3 + PHS;
        const float* Q0 = kqvp3 + 2 * (size_t)PHS;
        const float* Q1 = kqvp3 + 3 * (size_t)PHS;
        const float* V0 = kqvp3 + 4 * (size_t)PHS;
        const float* V1 = kqvp3 + 5 * (size_t)PHS;

        float* ka    = smem;          // 512
        float* sp    = smem + 512;    // 260
        float* smv   = smem + 772;    // 65
        float* p     = smem + 837;    // 65
        float* att_s = smem + 902;    // 64

        ka[tid]       = K0[(size_t)64 * H + tid]       + K1[(size_t)64 * H + tid];
        ka[tid + 256] = K0[(size_t)64 * H + tid + 256] + K1[(size_t)64 * H + tid + 256];
        __syncthreads();

        {
            int b = tid & 63;
            int t = tid >> 6;
            sp[t * 65 + b] = score_part(Q0, Q1, ka, b, t);
            if (tid < 4) sp[tid * 65 + 64] = score_part(Q0, Q1, ka, 64, tid);
        }
        __syncthreads();

        if (tid < S) {
            smv[tid] = (sp[tid] + sp[65 + tid]) + (sp[130 + tid] + sp[195 + tid]);
        }
        __syncthreads();

        float maxv = -INFINITY;
        for (int i = 0; i < S; ++i) maxv = fmaxf(maxv, smv[i]);
        float sum = 0.0f;
        for (int i = 0; i < S; ++i) sum += expf(smv[i] - maxv);
        float inv = 1.0f / sum;
        if (tid < S) p[tid] = expf(smv[tid] - maxv) * inv;
        __syncthreads();

        if (tid < 64) {
            int hh = j0 + tid;
            float a0 = 0.f, a1 = 0.f;
#pragma unroll 4
            for (int b = 0; b < 64; b += 2) {
                a0 = fmaf(p[b    ], V0[(size_t)(b    ) * H + hh] + V1[(size_t)(b    ) * H + hh], a0);
                a1 = fmaf(p[b + 1], V0[(size_t)(b + 1) * H + hh] + V1[(size_t)(b + 1) * H + hh], a1);
            }
            a0 = fmaf(p[64], V0[(size_t)64 * H + hh] + V1[(size_t)64 * H + hh], a0);
            att_s[tid] = a0 + a1;
        }
        __syncthreads();

        int jbase = ks * 64;
        float a0 = 0.f, a1 = 0.f, a2 = 0.f, a3 = 0.f;
        for (int j = 0; j < 64; j += 4) {
            a0 = fmaf(att_s[j + 0], lin3[(size_t)(jbase + j + 0) * 1024 + j2], a0);
            a1 = fmaf(att_s[j + 1], lin3[(size_t)(jbase + j + 1) * 1024 + j2], a1);
            a2 = fmaf(att_s[j + 2], lin3[(size_t)(jbase + j + 2) * 1024 + j2], a2);
            a3 = fmaf(att_s[j + 3], lin3[(size_t)(jbase + j + 3) * 1024 + j2], a3);
        }
        st1cv(tpart + ks * 1024 + j2, (a0 + a1) + (a2 + a3));
        __syncthreads();
    }
    gbarx(slots + (size_t)bi * 9 * 32, xcd, cen, nx); ++bi;

    // ---- P11: lin4 partials, 32 tasks ----
    for (int task = bid; task < 32; task += nbk) {
        int xb = task & 1;
        int ks = task >> 1;
        float* tl = smem;             // 64
        int hh = xb * 256 + tid;
        int j2base = ks * 64;

        if (tid < 64) {
            int j2 = j2base + tid;
            float s = 0.f;
#pragma unroll
            for (int p = 0; p < KS3; ++p) s += tpart[p * 1024 + j2];
            tl[tid] = fmaxf(s, 0.f);
        }
        __syncthreads();

        float a0 = 0.f, a1 = 0.f, a2 = 0.f, a3 = 0.f;
        for (int j = 0; j < 64; j += 4) {
            a0 = fmaf(tl[j + 0], lin4[(size_t)(j2base + j + 0) * H + hh], a0);
            a1 = fmaf(tl[j + 1], lin4[(size_t)(j2base + j + 1) * H + hh], a1);
            a2 = fmaf(tl[j + 2], lin4[(size_t)(j2base + j + 2) * H + hh], a2);
            a3 = fmaf(tl[j + 3], lin4[(size_t)(j2base + j + 3) * H + hh], a3);
        }
        st1cv(upart + ks * H + hh, (a0 + a1) + (a2 + a3));
        __syncthreads();
    }
    gbarx(slots + (size_t)bi * 9 * 32, xcd, cen, nx); ++bi;

    // ---- P12: tanh + lin5 -> out (block 0 only; exact original FP order) ----
    if (bid == 0) {
        float* u  = smem;             // 512
        float* pr = smem + 512;       // 8*64

#pragma unroll
        for (int r = 0; r < 2; ++r) {
            int h = tid + r * 256;
            float s = 0.f;
#pragma unroll
            for (int p = 0; p < KS4; ++p) s += upart[p * H + h];
            u[h] = tanhf(s);
        }
        __syncthreads();

        int o   = tid & 63;
        int sl0 = tid >> 6;           // 0..3
#pragma unroll
        for (int r = 0; r < 2; ++r) {
            int sl = sl0 + r * 4;     // 0..7 (matches original 8-slice split)
            int h0 = sl * 64;
            float acc = 0.f;
#pragma unroll 8
            for (int j = 0; j < 64; ++j) {
                acc = fmaf(u[h0 + j], lin5[(h0 + j) * 64 + o], acc);
            }
            pr[sl * 64 + o] = acc;
        }
        __syncthreads();

        if (tid < 64) {
            float s = 0.f;
#pragma unroll
            for (int p = 0; p < 8; ++p) s += pr[p * 64 + tid];
            out[tid] = s;
        }
    }
}

// ---------------------------------------------------------------------------
extern "C" void kernel_launch(void* const* d_in, const int* in_sizes, int n_in,
                              void* d_out, int out_size, void* d_ws, size_t ws_size,
                              hipStream_t stream) {
    const float* inputs  = (const float*)d_in[0];
    const float* emb     = (const float*)d_in[1];
    const float* wq      = (const float*)d_in[2];
    const float* wk      = (const float*)d_in[3];
    const float* wv      = (const float*)d_in[4];
    const float* linear1 = (const float*)d_in[5];
    const float* linear2 = (const float*)d_in[6];
    const float* linear3 = (const float*)d_in[7];
    const float* linear4 = (const float*)d_in[8];
    const float* linear5 = (const float*)d_in[9];
    float* out = (float*)d_out;
    float* ws  = (float*)d_ws;

    // Barrier region after all live data: 48*PHS + 24*1024 + 16*512 floats.
    size_t bar_off_floats = (size_t)48 * PHS + KS3 * 1024 + KS4 * 512;
    void* bar_ptr = (void*)(ws + bar_off_floats);
    hipMemsetAsync(bar_ptr, 0, (256 + NSLOT * 9 * 32) * sizeof(unsigned), stream);

    reversi_mega<<<dim3(GRID), dim3(256), 0, stream>>>(
        inputs, emb, wq, wk, wv, linear1, linear2, linear3, linear4, linear5,
        out, ws);
}

// Round 8
// 253.672 us; speedup vs baseline: 1.8931x; 1.8931x over previous
//
#include <hip/hip_runtime.h>
#include <math.h>

#define H 512
#define S 65
#define SP 80               // padded s-dimension (rows 65..79 zero/garbage)
#define HS (H * S)          // 33280
#define PHS (H * SP)        // 40960
#define KS3 24
#define KS4 16
#define GRID 256            // = #CUs; 1 block/CU always resident (no deadlock
                            // at any VGPR count); launch_bounds uncapped
#define NSLOT 12            // 1 registration + 11 data barriers

// Workspace layout (all buffers WRITE-ONCE per run -> no stale-line hazard):
//  y: PHS        kqvp: 18*PHS (layer1)   att1: 3*PHS   att2: PHS
//  plin1: 6*PHS  plin2: 6*PHS           kqvp2: 6*PHS  kqvp3: 6*PHS
//  y2: PHS       tpart: 24*1024         upart: 16*512
//  bar: census 8*32 u32 + NSLOT slots of 9*32 u32 (zeroed by captured memset)
//
// Round 7 change: GRID 288->256 and __launch_bounds__(256) WITHOUT a
// min-blocks arg. The (256,2) bound forced a 128-VGPR cap (VGPR_Count was
// pinned at exactly 128) -> suspected scratch spills in the KQV inner loop.
// 256 blocks = 1/CU guaranteed, so the register allocator is free.

// ---------------------------------------------------------------------------
__device__ __forceinline__ void st1cv(float* p, float v) { *p = v; }
__device__ __forceinline__ void st4cv(float* p, float4 v) { *(float4*)p = v; }

// ---------------------------------------------------------------------------
// Registration barrier (no flush; nothing written yet). bid&7 classes.
// ---------------------------------------------------------------------------
__device__ __forceinline__ void gbar0(unsigned* slot, int bid) {
    __syncthreads();
    if (threadIdx.x == 0) {
        unsigned* sub    = slot + (bid & 7) * 32;
        unsigned* master = slot + 8 * 32;
        unsigned old = __hip_atomic_fetch_add(sub, 1u, __ATOMIC_RELAXED,
                                              __HIP_MEMORY_SCOPE_AGENT);
        if (old == (GRID / 8 - 1))
            __hip_atomic_fetch_add(master, 1u, __ATOMIC_RELAXED,
                                   __HIP_MEMORY_SCOPE_AGENT);
        while (__hip_atomic_load(master, __ATOMIC_RELAXED,
                                 __HIP_MEMORY_SCOPE_AGENT) < 8u)
            __builtin_amdgcn_s_sleep(2);
        asm volatile("" ::: "memory");
    }
    __syncthreads();
}

// ---------------------------------------------------------------------------
// Data barrier: last arriver per physical XCD flushes its L2 (one
// threadfence), then signals master. Pollers spin relaxed on master.
// ---------------------------------------------------------------------------
__device__ __forceinline__ void gbarx(unsigned* slot, unsigned xcd,
                                      unsigned census, unsigned nxcd) {
    __syncthreads();
    if (threadIdx.x == 0) {
        unsigned* sub    = slot + xcd * 32;
        unsigned* master = slot + 8 * 32;
        asm volatile("s_waitcnt vmcnt(0)" ::: "memory");   // stores in L2
        unsigned old = __hip_atomic_fetch_add(sub, 1u, __ATOMIC_RELAXED,
                                              __HIP_MEMORY_SCOPE_AGENT);
        if (old == census - 1u) {
            __threadfence();       // wbl2(+inv) for THIS XCD's L2 -> LLC
            __hip_atomic_fetch_add(master, 1u, __ATOMIC_RELAXED,
                                   __HIP_MEMORY_SCOPE_AGENT);
        }
        while (__hip_atomic_load(master, __ATOMIC_RELAXED,
                                 __HIP_MEMORY_SCOPE_AGENT) < nxcd)
            __builtin_amdgcn_s_sleep(16);
        asm volatile("" ::: "memory");
    }
    __syncthreads();
}

// ---------------------------------------------------------------------------
__device__ __forceinline__ void mac4(float4& c, float ax, float ay, float az,
                                     float aw, const float4& w0, const float4& w1,
                                     const float4& w2, const float4& w3) {
    c.x = fmaf(ax, w0.x, c.x); c.y = fmaf(ax, w0.y, c.y);
    c.z = fmaf(ax, w0.z, c.z); c.w = fmaf(ax, w0.w, c.w);
    c.x = fmaf(ay, w1.x, c.x); c.y = fmaf(ay, w1.y, c.y);
    c.z = fmaf(ay, w1.z, c.z); c.w = fmaf(ay, w1.w, c.w);
    c.x = fmaf(az, w2.x, c.x); c.y = fmaf(az, w2.y, c.y);
    c.z = fmaf(az, w2.z, c.z); c.w = fmaf(az, w2.w, c.w);
    c.x = fmaf(aw, w3.x, c.x); c.y = fmaf(aw, w3.y, c.y);
    c.z = fmaf(aw, w3.z, c.z); c.w = fmaf(aw, w3.w, c.w);
}

// ---------------------------------------------------------------------------
// KQV GEMM task (layers 2-3). Cached loads; plain stores.
// ---------------------------------------------------------------------------
__device__ __forceinline__ void kqv_task(const float* __restrict__ wq,
                                         const float* __restrict__ wk,
                                         const float* __restrict__ wv,
                                         int mat0,
                                         const float* __restrict__ yT,
                                         float* __restrict__ part,
                                         int task, int t,
                                         float* __restrict__ smem) {
    int slot  = task / 96;
    int r96   = task - slot * 96;
    int which = r96 >> 5;
    int xx    = r96 & 31;
    int mat   = mat0 + slot;
    const float* W = (which == 0 ? wk : (which == 1 ? wq : wv)) + (size_t)mat * H * H;

    int n0   = (xx & 15) * 32;
    int kidx = xx >> 4;

    float* Wt = smem;           // [64*32], swizzled
    float* As = smem + 2048;    // [SP*68], stride 68 conflict-free

    int nq = t & 7;
    int g  = t >> 3;
    bool r2 = (g < 16);

    float4 acc0 = {0,0,0,0}, acc1 = {0,0,0,0}, acc2 = {0,0,0,0};

    for (int ch = 0; ch < 4; ++ch) {
        int kc0 = kidx * 256 + ch * 64;
#pragma unroll
        for (int c = 0; c < 2; ++c) {
            int f = c * 256 + t;
            int wn  = f >> 4;
            int kf4 = f & 15;
            float4 w4 = *(const float4*)(W + (size_t)(n0 + wn) * H + kc0 + 4 * kf4);
            int sw = ((wn >> 2) ^ (kf4 & 7));
            int base = (4 * kf4) * 32 + 4 * sw + (wn & 3);
            Wt[base     ] = w4.x;
            Wt[base + 32] = w4.y;
            Wt[base + 64] = w4.z;
            Wt[base + 96] = w4.w;
        }
#pragma unroll
        for (int c = 0; c < 5; ++c) {
            int f = c * 256 + t;
            int as  = f >> 4;
            int kf4 = f & 15;
            *(float4*)(&As[as * 68 + 4 * kf4]) =
                *(const float4*)(yT + (size_t)as * H + kc0 + 4 * kf4);
        }
        __syncthreads();

#pragma unroll
        for (int k4 = 0; k4 < 16; ++k4) {
            int swc = 4 * (nq ^ (k4 & 7));
            float4 w0 = *(const float4*)(&Wt[(4 * k4 + 0) * 32 + swc]);
            float4 w1 = *(const float4*)(&Wt[(4 * k4 + 1) * 32 + swc]);
            float4 w2 = *(const float4*)(&Wt[(4 * k4 + 2) * 32 + swc]);
            float4 w3 = *(const float4*)(&Wt[(4 * k4 + 3) * 32 + swc]);
            {
                float4 a = *(const float4*)(&As[g * 68 + 4 * k4]);
                mac4(acc0, a.x, a.y, a.z, a.w, w0, w1, w2, w3);
            }
            {
                float4 a = *(const float4*)(&As[(g + 32) * 68 + 4 * k4]);
                mac4(acc1, a.x, a.y, a.z, a.w, w0, w1, w2, w3);
            }
            if (r2) {
                float4 a = *(const float4*)(&As[(g + 64) * 68 + 4 * k4]);
                mac4(acc2, a.x, a.y, a.z, a.w, w0, w1, w2, w3);
            }
        }
        __syncthreads();
    }

    float* P = part + (size_t)((slot * 3 + which) * 2 + kidx) * PHS;
    st4cv(P + (size_t)g * H + n0 + 4 * nq, acc0);
    st4cv(P + (size_t)(g + 32) * H + n0 + 4 * nq, acc1);
    if (r2) st4cv(P + (size_t)(g + 64) * H + n0 + 4 * nq, acc2);
}

// ---------------------------------------------------------------------------
// Layer-1 KQV with embed fused: As[s][k] = emb[k*S+s]*x[s] (bit-identical).
// ---------------------------------------------------------------------------
__device__ __forceinline__ void kqv1_task(const float* __restrict__ wq,
                                          const float* __restrict__ wk,
                                          const float* __restrict__ wv,
                                          const float* __restrict__ emb,
                                          float* __restrict__ part,
                                          int task, int t,
                                          float* __restrict__ smem,
                                          const float* __restrict__ xv) {
    int slot  = task / 96;
    int r96   = task - slot * 96;
    int which = r96 >> 5;
    int xx    = r96 & 31;
    const float* W = (which == 0 ? wk : (which == 1 ? wq : wv)) + (size_t)slot * H * H;

    int n0   = (xx & 15) * 32;
    int kidx = xx >> 4;

    float* Wt = smem;
    float* As = smem + 2048;

    int nq = t & 7;
    int g  = t >> 3;
    bool r2 = (g < 16);

    float4 acc0 = {0,0,0,0}, acc1 = {0,0,0,0}, acc2 = {0,0,0,0};

    for (int ch = 0; ch < 4; ++ch) {
        int kc0 = kidx * 256 + ch * 64;
#pragma unroll
        for (int c = 0; c < 2; ++c) {
            int f = c * 256 + t;
            int wn  = f >> 4;
            int kf4 = f & 15;
            float4 w4 = *(const float4*)(W + (size_t)(n0 + wn) * H + kc0 + 4 * kf4);
            int sw = ((wn >> 2) ^ (kf4 & 7));
            int base = (4 * kf4) * 32 + 4 * sw + (wn & 3);
            Wt[base     ] = w4.x;
            Wt[base + 32] = w4.y;
            Wt[base + 64] = w4.z;
            Wt[base + 96] = w4.w;
        }
#pragma unroll
        for (int c = 0; c < 5; ++c) {
            int f = c * 256 + t;
            int as  = (f & 15) + 16 * c;     // 0..79
            int kf4 = (f >> 4) & 15;         // 0..15
            int k0 = kc0 + 4 * kf4;
            float xs = xv[as];
            float4 v;
            v.x = emb[(size_t)(k0 + 0) * S + as] * xs;
            v.y = emb[(size_t)(k0 + 1) * S + as] * xs;
            v.z = emb[(size_t)(k0 + 2) * S + as] * xs;
            v.w = emb[(size_t)(k0 + 3) * S + as] * xs;
            *(float4*)(&As[as * 68 + 4 * kf4]) = v;
        }
        __syncthreads();

#pragma unroll
        for (int k4 = 0; k4 < 16; ++k4) {
            int swc = 4 * (nq ^ (k4 & 7));
            float4 w0 = *(const float4*)(&Wt[(4 * k4 + 0) * 32 + swc]);
            float4 w1 = *(const float4*)(&Wt[(4 * k4 + 1) * 32 + swc]);
            float4 w2 = *(const float4*)(&Wt[(4 * k4 + 2) * 32 + swc]);
            float4 w3 = *(const float4*)(&Wt[(4 * k4 + 3) * 32 + swc]);
            {
                float4 a = *(const float4*)(&As[g * 68 + 4 * k4]);
                mac4(acc0, a.x, a.y, a.z, a.w, w0, w1, w2, w3);
            }
            {
                float4 a = *(const float4*)(&As[(g + 32) * 68 + 4 * k4]);
                mac4(acc1, a.x, a.y, a.z, a.w, w0, w1, w2, w3);
            }
            if (r2) {
                float4 a = *(const float4*)(&As[(g + 64) * 68 + 4 * k4]);
                mac4(acc2, a.x, a.y, a.z, a.w, w0, w1, w2, w3);
            }
        }
        __syncthreads();
    }

    float* P = part + (size_t)((slot * 3 + which) * 2 + kidx) * PHS;
    st4cv(P + (size_t)g * H + n0 + 4 * nq, acc0);
    st4cv(P + (size_t)(g + 32) * H + n0 + 4 * nq, acc1);
    if (r2) st4cv(P + (size_t)(g + 64) * H + n0 + 4 * nq, acc2);
}

// ---------------------------------------------------------------------------
__device__ __forceinline__ float score_part(const float* __restrict__ Q0,
                                            const float* __restrict__ Q1,
                                            const float* __restrict__ ka,
                                            int b, int t) {
    const float4* q0 = (const float4*)(Q0 + (size_t)b * H) + t * 32;
    const float4* q1 = (const float4*)(Q1 + (size_t)b * H) + t * 32;
    const float4* kl = (const float4*)ka + t * 32;
    float4 c0 = {0,0,0,0}, c1 = {0,0,0,0};
#pragma unroll
    for (int u = 0; u < 32; u += 2) {
        float4 qa = q0[u], qb = q1[u], k0 = kl[u];
        float4 qc = q0[u+1], qd = q1[u+1], k1 = kl[u+1];
        c0.x = fmaf(k0.x, qa.x + qb.x, c0.x);
        c0.y = fmaf(k0.y, qa.y + qb.y, c0.y);
        c0.z = fmaf(k0.z, qa.z + qb.z, c0.z);
        c0.w = fmaf(k0.w, qa.w + qb.w, c0.w);
        c1.x = fmaf(k1.x, qc.x + qd.x, c1.x);
        c1.y = fmaf(k1.y, qc.y + qd.y, c1.y);
        c1.z = fmaf(k1.z, qc.z + qd.z, c1.z);
        c1.w = fmaf(k1.w, qc.w + qd.w, c1.w);
    }
    return ((c0.x + c0.y) + (c0.z + c0.w)) + ((c1.x + c1.y) + (c1.z + c1.w));
}

// ---------------------------------------------------------------------------
__device__ __forceinline__ void attn_task(const float* __restrict__ base,
                                          float* __restrict__ ao,
                                          int a, int tid,
                                          float* __restrict__ smem) {
    const float* K0 = base;
    const float* K1 = base + PHS;
    const float* Q0 = base + 2 * (size_t)PHS;
    const float* Q1 = base + 3 * (size_t)PHS;
    const float* V0 = base + 4 * (size_t)PHS;
    const float* V1 = base + 5 * (size_t)PHS;

    float* ka  = smem;          // 512
    float* sp  = smem + 512;    // 4*65
    float* smv = smem + 772;    // 65
    float* p   = smem + 837;    // 65

    ka[tid]       = K0[(size_t)a * H + tid]       + K1[(size_t)a * H + tid];
    ka[tid + 256] = K0[(size_t)a * H + tid + 256] + K1[(size_t)a * H + tid + 256];
    __syncthreads();

    {
        int b = tid & 63;
        int t = tid >> 6;
        sp[t * 65 + b] = score_part(Q0, Q1, ka, b, t);
        if (tid < 4) sp[tid * 65 + 64] = score_part(Q0, Q1, ka, 64, tid);
    }
    __syncthreads();

    if (tid < S) {
        smv[tid] = (sp[tid] + sp[65 + tid]) + (sp[130 + tid] + sp[195 + tid]);
    }
    __syncthreads();

    float maxv = -INFINITY;
    for (int i = 0; i < S; ++i) maxv = fmaxf(maxv, smv[i]);
    float sum = 0.0f;
    for (int i = 0; i < S; ++i) sum += expf(smv[i] - maxv);
    float inv = 1.0f / sum;
    if (tid < S) p[tid] = expf(smv[tid] - maxv) * inv;
    __syncthreads();

#pragma unroll
    for (int rep = 0; rep < 2; ++rep) {
        int hh = tid + rep * 256;
        float a0 = 0.f, a1 = 0.f;
#pragma unroll 4
        for (int b = 0; b < 64; b += 2) {
            a0 = fmaf(p[b    ], V0[(size_t)(b    ) * H + hh] + V1[(size_t)(b    ) * H + hh], a0);
            a1 = fmaf(p[b + 1], V0[(size_t)(b + 1) * H + hh] + V1[(size_t)(b + 1) * H + hh], a1);
        }
        a0 = fmaf(p[64], V0[(size_t)64 * H + hh] + V1[(size_t)64 * H + hh], a0);
        st1cv(ao + hh, a0 + a1);
    }
    __syncthreads();
}

// ---------------------------------------------------------------------------
__device__ __forceinline__ void lin4row_dev(float* __restrict__ smem,
                                            const float* __restrict__ att,
                                            int col0,
                                            const float* __restrict__ L,
                                            float* __restrict__ dst,
                                            int s0, int tid) {
    float* Ar   = smem;                          // 4*256
    float4* red = (float4*)(smem + 1024);        // 4*128 float4

    {
        int rr = tid >> 6;
        int cc = tid & 63;
        *(float4*)(&Ar[rr * 256 + cc * 4]) =
            *(const float4*)(att + (size_t)(s0 + rr) * H + col0 + cc * 4);
    }
    __syncthreads();

    int h4 = (tid & 127) * 4;
    int jh = tid >> 7;
    const float* Lj = L + (size_t)(jh * 128) * H + h4;
    const float* A0 = Ar + jh * 128;

    float4 c0 = {0,0,0,0}, c1 = {0,0,0,0}, c2 = {0,0,0,0}, c3 = {0,0,0,0};
#pragma unroll 8
    for (int j = 0; j < 128; ++j) {
        float4 L4 = *(const float4*)(Lj + (size_t)j * H);
        float a0 = A0[j], a1 = A0[256 + j], a2 = A0[512 + j], a3 = A0[768 + j];
        c0.x = fmaf(a0, L4.x, c0.x); c0.y = fmaf(a0, L4.y, c0.y);
        c0.z = fmaf(a0, L4.z, c0.z); c0.w = fmaf(a0, L4.w, c0.w);
        c1.x = fmaf(a1, L4.x, c1.x); c1.y = fmaf(a1, L4.y, c1.y);
        c1.z = fmaf(a1, L4.z, c1.z); c1.w = fmaf(a1, L4.w, c1.w);
        c2.x = fmaf(a2, L4.x, c2.x); c2.y = fmaf(a2, L4.y, c2.y);
        c2.z = fmaf(a2, L4.z, c2.z); c2.w = fmaf(a2, L4.w, c2.w);
        c3.x = fmaf(a3, L4.x, c3.x); c3.y = fmaf(a3, L4.y, c3.y);
        c3.z = fmaf(a3, L4.z, c3.z); c3.w = fmaf(a3, L4.w, c3.w);
    }

    if (jh == 1) {
        int x = tid & 127;
        red[x] = c0; red[128 + x] = c1; red[256 + x] = c2; red[384 + x] = c3;
    }
    __syncthreads();
    if (jh == 0) {
        float4 r0 = red[tid], r1 = red[128 + tid], r2 = red[256 + tid], r3 = red[384 + tid];
        c0.x += r0.x; c0.y += r0.y; c0.z += r0.z; c0.w += r0.w;
        c1.x += r1.x; c1.y += r1.y; c1.z += r1.z; c1.w += r1.w;
        c2.x += r2.x; c2.y += r2.y; c2.z += r2.z; c2.w += r2.w;
        c3.x += r3.x; c3.y += r3.y; c3.z += r3.z; c3.w += r3.w;
        st4cv(dst + (size_t)(s0 + 0) * H + h4, c0);
        st4cv(dst + (size_t)(s0 + 1) * H + h4, c1);
        st4cv(dst + (size_t)(s0 + 2) * H + h4, c2);
        st4cv(dst + (size_t)(s0 + 3) * H + h4, c3);
    }
    __syncthreads();
}

// ---------------------------------------------------------------------------
__device__ __forceinline__ void lin3_slice(const float* __restrict__ att1,
                                           const float* __restrict__ lin3,
                                           float* __restrict__ tpart,
                                           int idx, int tid) {
    int j2 = (idx & 3) * 256 + tid;
    int ks = idx >> 2;                    // 0..15
    const float* row = att1 + (size_t)(ks >> 3) * PHS + (size_t)64 * H;
    int j0 = (ks & 7) * 64;
    int jbase = ks * 64;
    float a0 = 0.f, a1 = 0.f, a2 = 0.f, a3 = 0.f;
    for (int j = 0; j < 64; j += 4) {
        a0 = fmaf(row[j0 + j + 0], lin3[(size_t)(jbase + j + 0) * 1024 + j2], a0);
        a1 = fmaf(row[j0 + j + 1], lin3[(size_t)(jbase + j + 1) * 1024 + j2], a1);
        a2 = fmaf(row[j0 + j + 2], lin3[(size_t)(jbase + j + 2) * 1024 + j2], a2);
        a3 = fmaf(row[j0 + j + 3], lin3[(size_t)(jbase + j + 3) * 1024 + j2], a3);
    }
    st1cv(tpart + ks * 1024 + j2, (a0 + a1) + (a2 + a3));
}

// ---------------------------------------------------------------------------
__global__ void __launch_bounds__(256)
reversi_mega(const float* __restrict__ inputs, const float* __restrict__ emb,
             const float* __restrict__ wq, const float* __restrict__ wk,
             const float* __restrict__ wv, const float* __restrict__ lin1,
             const float* __restrict__ lin2, const float* __restrict__ lin3,
             const float* __restrict__ lin4, const float* __restrict__ lin5,
             float* __restrict__ out, float* __restrict__ ws) {
    __shared__ __align__(16) float smem[7568];   // 30272 B (union + xv[80])
    __shared__ unsigned sxcd, scen, snx;

    float* y     = ws;                  // layer-1 output (P4)
    float* kqvp  = y     + PHS;         // 18*PHS layer-1 kqv (P1)
    float* att1  = kqvp  + 18 * PHS;    // 3*PHS  (P2)
    float* att2  = att1  + 3 * PHS;     // PHS    (P6)
    float* plin1 = att2  + PHS;         // 6*PHS  (P3)
    float* plin2 = plin1 + 6 * PHS;     // 6*PHS  (P3 segs0-3, P7 segs4-5)
    float* kqvp2 = plin2 + 6 * PHS;     // 6*PHS  layer-2 kqv (P5)
    float* kqvp3 = kqvp2 + 6 * PHS;     // 6*PHS  layer-3 kqv (P9)
    float* y2    = kqvp3 + 6 * PHS;     // PHS    layer-2 output (P8)
    float* tpart = y2    + PHS;         // 24*1024
    float* upart = tpart + KS3 * 1024;  // 16*512
    unsigned* bar    = (unsigned*)(upart + KS4 * 512);
    unsigned* census = bar;             // 8 counters, 128 B apart
    unsigned* slots  = bar + 256;       // NSLOT slots of 9*32

    int tid  = threadIdx.x;
    int bid  = blockIdx.x;
    int nbk  = gridDim.x;
    int cls  = bid & 7;     // task-partition class
    int rank = bid >> 3;    // 0..31 within class

    // ---- registration: physical-XCD census, then full-grid barrier ----
    if (tid == 0) {
        unsigned x;
        asm volatile("s_getreg_b32 %0, hwreg(HW_REG_XCC_ID)" : "=s"(x));
        x &= 7u;
        sxcd = x;
        __hip_atomic_fetch_add(census + x * 32, 1u, __ATOMIC_RELAXED,
                               __HIP_MEMORY_SCOPE_AGENT);
    }
    __syncthreads();
    gbar0(slots, bid);
    if (tid == 0) {
        unsigned n = 0, c = 0;
        for (int i = 0; i < 8; ++i) {
            unsigned v = __hip_atomic_load(census + i * 32, __ATOMIC_RELAXED,
                                           __HIP_MEMORY_SCOPE_AGENT);
            if (v) ++n;
            if ((unsigned)i == sxcd) c = v;
        }
        scen = c; snx = n;
    }
    __syncthreads();
    unsigned xcd = sxcd, cen = scen, nx = snx;
    int bi = 1;

    // ---- P1: layer-1 KQV (mats 0..2), embed fused, 288 tasks strided ----
    float* xv = smem + 7488;
    if (tid < 80) {
        float xvv = 0.f;
        if (tid < S) xvv = (tid == 64) ? 1.0f : inputs[tid];
        xv[tid] = xvv;
    }
    __syncthreads();
    for (int task = bid; task < 288; task += nbk)
        kqv1_task(wq, wk, wv, emb, kqvp, task, tid, smem, xv);
    gbarx(slots + (size_t)bi * 9 * 32, xcd, cen, nx); ++bi;

    // ---- P2: layer-1 attention, 195 tasks, slot-affine classes ----
    {
        int slot, r;
        if (cls < 3)      { slot = 0; r = cls * 32 + rank; }
        else if (cls < 6) { slot = 1; r = (cls - 3) * 32 + rank; }
        else              { slot = 2; r = (cls - 6) * 32 + rank; }
        if (cls == 2 && rank == 31) { slot = 2; r = 64; }   // cover slot2 r=64
        if (r < 65)
            attn_task(kqvp + (size_t)slot * 6 * PHS,
                      att1 + (size_t)slot * PHS + (size_t)r * H, r, tid, smem);
    }
    gbarx(slots + (size_t)bi * 9 * 32, xcd, cen, nx); ++bi;

    // ---- P3: mega_lin, 234 tasks, seg-affine classes ----
    // lin1: cls0-5 x p0-16 (102). lin2 seg0,1 -> cls6; seg2,3 -> cls7;
    // seg1/seg3 p15,16 via lin1-spare overflow. lin3 slices 0..63 via spares.
    {
        if (cls < 6) {
            if (rank < 17) {
                int seg = cls;
                lin4row_dev(smem, att1 + (size_t)(seg >> 1) * PHS,
                            (seg & 1) * 256, lin1 + (size_t)(seg * 256) * H,
                            plin1 + (size_t)seg * PHS, rank * 4, tid);
            } else {
                int spare = cls * 15 + (rank - 17);   // 0..89
                if (spare < 64) {
                    lin3_slice(att1, lin3, tpart, spare, tid);
                } else {
                    int s2 = spare - 64;              // 0..25
                    if (s2 < 4) {
                        int seg = (s2 < 2) ? 1 : 3;
                        int pp  = 15 + (s2 & 1);
                        lin4row_dev(smem, att1 + (size_t)(seg >> 1) * PHS,
                                    (seg & 1) * 256,
                                    lin2 + (size_t)(seg * 256) * H,
                                    plin2 + (size_t)seg * PHS, pp * 4, tid);
                    }
                }
            }
        } else {
            int base2 = (cls - 6) * 2;                // cls6->segs0,1 cls7->2,3
            if (rank < 17) {
                int seg = base2;
                lin4row_dev(smem, att1 + (size_t)(seg >> 1) * PHS,
                            (seg & 1) * 256, lin2 + (size_t)(seg * 256) * H,
                            plin2 + (size_t)seg * PHS, rank * 4, tid);
            } else {
                int seg = base2 + 1;
                int pp = rank - 17;                   // 0..14
                lin4row_dev(smem, att1 + (size_t)(seg >> 1) * PHS,
                            (seg & 1) * 256, lin2 + (size_t)(seg * 256) * H,
                            plin2 + (size_t)seg * PHS, pp * 4, tid);
            }
        }
    }
    gbarx(slots + (size_t)bi * 9 * 32, xcd, cen, nx); ++bi;

    // ---- P4: combine plin1 -> y (relu); pad rows zeroed ----
    for (int task = bid; task < PHS / 256; task += nbk) {
        int i = task * 256 + tid;
        if (i < HS) {
            float s = 0.f;
#pragma unroll
            for (int p = 0; p < 6; ++p) s += plin1[(size_t)p * PHS + i];
            st1cv(y + i, fmaxf(s, 0.0f));
        } else {
            st1cv(y + i, 0.f);
        }
    }
    gbarx(slots + (size_t)bi * 9 * 32, xcd, cen, nx); ++bi;

    // ---- P5: layer-2 KQV (mat 5) -> kqvp2, 96 tasks ----
    for (int task = bid; task < 96; task += nbk)
        kqv_task(wq, wk, wv, 5, y, kqvp2, task, tid, smem);
    gbarx(slots + (size_t)bi * 9 * 32, xcd, cen, nx); ++bi;

    // ---- P6: layer-2 attention, 65 tasks, classes 0,1 (+1 spare) ----
    {
        int r = -1;
        if (cls < 2) r = cls * 32 + rank;             // 0..63
        else if (cls == 2 && rank == 0) r = 64;
        if (r >= 0 && r < 65)
            attn_task(kqvp2, att2 + (size_t)r * H, r, tid, smem);
    }
    gbarx(slots + (size_t)bi * 9 * 32, xcd, cen, nx); ++bi;

    // ---- P7: lin2 segs 4,5 from att2 ----
    if (cls < 2 && rank < 17) {
        int seg = 4 + cls;
        lin4row_dev(smem, att2, (seg & 1) * 256, lin2 + (size_t)(seg * 256) * H,
                    plin2 + (size_t)seg * PHS, rank * 4, tid);
    }
    gbarx(slots + (size_t)bi * 9 * 32, xcd, cen, nx); ++bi;

    // ---- P8: combine plin2 -> y2 (relu); pads zeroed ----
    for (int task = bid; task < PHS / 256; task += nbk) {
        int i = task * 256 + tid;
        if (i < HS) {
            float s = 0.f;
#pragma unroll
            for (int p = 0; p < 6; ++p) s += plin2[(size_t)p * PHS + i];
            st1cv(y2 + i, fmaxf(s, 0.0f));
        } else {
            st1cv(y2 + i, 0.f);
        }
    }
    gbarx(slots + (size_t)bi * 9 * 32, xcd, cen, nx); ++bi;

    // ---- P9: layer-3 KQV (mat 8) -> kqvp3, 96 tasks ----
    for (int task = bid; task < 96; task += nbk)
        kqv_task(wq, wk, wv, 8, y2, kqvp3, task, tid, smem);
    gbarx(slots + (size_t)bi * 9 * 32, xcd, cen, nx); ++bi;

    // ---- P10: layer-3 attention (row 64) + lin3 slices 16..23 ----
    if (cls < 4 && rank < 8) {
        int task = cls * 8 + rank;            // 0..31
        int xb = task & 3;
        int ks = 16 + (task >> 2);
        int j2 = xb * 256 + tid;
        int j0 = (ks & 7) * 64;

        const float* K0 = kqvp3;
        const float* K1 = kqvp3 + PHS;
        const float* Q0 = kqvp3 + 2 * (size_t)PHS;
        const float* Q1 = kqvp3 + 3 * (size_t)PHS;
        const float* V0 = kqvp3 + 4 * (size_t)PHS;
        const float* V1 = kqvp3 + 5 * (size_t)PHS;

        float* ka    = smem;          // 512
        float* sp    = smem + 512;    // 260
        float* smv   = smem + 772;    // 65
        float* p     = smem + 837;    // 65
        float* att_s = smem + 902;    // 64

        ka[tid]       = K0[(size_t)64 * H + tid]       + K1[(size_t)64 * H + tid];
        ka[tid + 256] = K0[(size_t)64 * H + tid + 256] + K1[(size_t)64 * H + tid + 256];
        __syncthreads();

        {
            int b = tid & 63;
            int t = tid >> 6;
            sp[t * 65 + b] = score_part(Q0, Q1, ka, b, t);
            if (tid < 4) sp[tid * 65 + 64] = score_part(Q0, Q1, ka, 64, tid);
        }
        __syncthreads();

        if (tid < S) {
            smv[tid] = (sp[tid] + sp[65 + tid]) + (sp[130 + tid] + sp[195 + tid]);
        }
        __syncthreads();

        float maxv = -INFINITY;
        for (int i = 0; i < S; ++i) maxv = fmaxf(maxv, smv[i]);
        float sum = 0.0f;
        for (int i = 0; i < S; ++i) sum += expf(smv[i] - maxv);
        float inv = 1.0f / sum;
        if (tid < S) p[tid] = expf(smv[tid] - maxv) * inv;
        __syncthreads();

        if (tid < 64) {
            int hh = j0 + tid;
            float a0 = 0.f, a1 = 0.f;
#pragma unroll 4
            for (int b = 0; b < 64; b += 2) {
                a0 = fmaf(p[b    ], V0[(size_t)(b    ) * H + hh] + V1[(size_t)(b    ) * H + hh], a0);
                a1 = fmaf(p[b + 1], V0[(size_t)(b + 1) * H + hh] + V1[(size_t)(b + 1) * H + hh], a1);
            }
            a0 = fmaf(p[64], V0[(size_t)64 * H + hh] + V1[(size_t)64 * H + hh], a0);
            att_s[tid] = a0 + a1;
        }
        __syncthreads();

        int jbase = ks * 64;
        float a0 = 0.f, a1 = 0.f, a2 = 0.f, a3 = 0.f;
        for (int j = 0; j < 64; j += 4) {
            a0 = fmaf(att_s[j + 0], lin3[(size_t)(jbase + j + 0) * 1024 + j2], a0);
            a1 = fmaf(att_s[j + 1], lin3[(size_t)(jbase + j + 1) * 1024 + j2], a1);
            a2 = fmaf(att_s[j + 2], lin3[(size_t)(jbase + j + 2) * 1024 + j2], a2);
            a3 = fmaf(att_s[j + 3], lin3[(size_t)(jbase + j + 3) * 1024 + j2], a3);
        }
        st1cv(tpart + ks * 1024 + j2, (a0 + a1) + (a2 + a3));
        __syncthreads();
    }
    gbarx(slots + (size_t)bi * 9 * 32, xcd, cen, nx); ++bi;

    // ---- P11: lin4 partials, 32 tasks ----
    for (int task = bid; task < 32; task += nbk) {
        int xb = task & 1;
        int ks = task >> 1;
        float* tl = smem;             // 64
        int hh = xb * 256 + tid;
        int j2base = ks * 64;

        if (tid < 64) {
            int j2 = j2base + tid;
            float s = 0.f;
#pragma unroll
            for (int p = 0; p < KS3; ++p) s += tpart[p * 1024 + j2];
            tl[tid] = fmaxf(s, 0.f);
        }
        __syncthreads();

        float a0 = 0.f, a1 = 0.f, a2 = 0.f, a3 = 0.f;
        for (int j = 0; j < 64; j += 4) {
            a0 = fmaf(tl[j + 0], lin4[(size_t)(j2base + j + 0) * H + hh], a0);
            a1 = fmaf(tl[j + 1], lin4[(size_t)(j2base + j + 1) * H + hh], a1);
            a2 = fmaf(tl[j + 2], lin4[(size_t)(j2base + j + 2) * H + hh], a2);
            a3 = fmaf(tl[j + 3], lin4[(size_t)(j2base + j + 3) * H + hh], a3);
        }
        st1cv(upart + ks * H + hh, (a0 + a1) + (a2 + a3));
        __syncthreads();
    }
    gbarx(slots + (size_t)bi * 9 * 32, xcd, cen, nx); ++bi;

    // ---- P12: tanh + lin5 -> out (block 0 only; exact original FP order) ----
    if (bid == 0) {
        float* u  = smem;             // 512
        float* pr = smem + 512;       // 8*64

#pragma unroll
        for (int r = 0; r < 2; ++r) {
            int h = tid + r * 256;
            float s = 0.f;
#pragma unroll
            for (int p = 0; p < KS4; ++p) s += upart[p * H + h];
            u[h] = tanhf(s);
        }
        __syncthreads();

        int o   = tid & 63;
        int sl0 = tid >> 6;           // 0..3
#pragma unroll
        for (int r = 0; r < 2; ++r) {
            int sl = sl0 + r * 4;     // 0..7 (matches original 8-slice split)
            int h0 = sl * 64;
            float acc = 0.f;
#pragma unroll 8
            for (int j = 0; j < 64; ++j) {
                acc = fmaf(u[h0 + j], lin5[(h0 + j) * 64 + o], acc);
            }
            pr[sl * 64 + o] = acc;
        }
        __syncthreads();

        if (tid < 64) {
            float s = 0.f;
#pragma unroll
            for (int p = 0; p < 8; ++p) s += pr[p * 64 + tid];
            out[tid] = s;
        }
    }
}

// ---------------------------------------------------------------------------
extern "C" void kernel_launch(void* const* d_in, const int* in_sizes, int n_in,
                              void* d_out, int out_size, void* d_ws, size_t ws_size,
                              hipStream_t stream) {
    const float* inputs  = (const float*)d_in[0];
    const float* emb     = (const float*)d_in[1];
    const float* wq      = (const float*)d_in[2];
    const float* wk      = (const float*)d_in[3];
    const float* wv      = (const float*)d_in[4];
    const float* linear1 = (const float*)d_in[5];
    const float* linear2 = (const float*)d_in[6];
    const float* linear3 = (const float*)d_in[7];
    const float* linear4 = (const float*)d_in[8];
    const float* linear5 = (const float*)d_in[9];
    float* out = (float*)d_out;
    float* ws  = (float*)d_ws;

    // Barrier region after all live data: 48*PHS + 24*1024 + 16*512 floats.
    size_t bar_off_floats = (size_t)48 * PHS + KS3 * 1024 + KS4 * 512;
    void* bar_ptr = (void*)(ws + bar_off_floats);
    hipMemsetAsync(bar_ptr, 0, (256 + NSLOT * 9 * 32) * sizeof(unsigned), stream);

    reversi_mega<<<dim3(GRID), dim3(256), 0, stream>>>(
        inputs, emb, wq, wk, wv, linear1, linear2, linear3, linear4, linear5,
        out, ws);
}